// Round 2
// 724.206 us; speedup vs baseline: 1.0871x; 1.0871x over previous
//
#include <hip/hip_runtime.h>
#include <hip/hip_bf16.h>

typedef __bf16 bf16_t;
typedef bf16_t bf16x4 __attribute__((ext_vector_type(4)));
typedef bf16_t bf16x8 __attribute__((ext_vector_type(8)));
typedef float f32x4 __attribute__((ext_vector_type(4)));

static constexpr int N_NODES = 50000;
static constexpr int N_EDGES = 1600000;
static constexpr int FIN = 1280;
static constexpr int HD = 128;
static constexpr int NG = 64;
// 0.5/sqrt(pi)/sqrt(128)
static constexpr float TP_NORM_F = 0.0249338908f;

// ---- fused weight prep: transpose+cast lin_w (scale 1) and tp_w1/tp_w2 (scale TP_NORM)
__global__ __launch_bounds__(256) void k_prep(const float* __restrict__ lin_w,
                                              const float* __restrict__ tp1,
                                              const float* __restrict__ tp2,
                                              bf16_t* __restrict__ WtL,
                                              bf16_t* __restrict__ Wt1,
                                              bf16_t* __restrict__ Wt2) {
  int idx = blockIdx.x * 256 + threadIdx.x;
  const int totL = FIN * HD;      // 163840
  const int tot1 = HD * HD;       // 16384
  if (idx < totL) {
    int k = idx >> 7, n = idx & 127;
    WtL[n * FIN + k] = (bf16_t)lin_w[idx];
  } else if (idx < totL + tot1) {
    int j = idx - totL;
    int k = j >> 7, n = j & 127;
    Wt1[n * HD + k] = (bf16_t)(tp1[j] * TP_NORM_F);
  } else if (idx < totL + 2 * tot1) {
    int j = idx - totL - tot1;
    int k = j >> 7, n = j & 127;
    Wt2[n * HD + k] = (bf16_t)(tp2[j] * TP_NORM_F);
  }
}

// ---- MFMA GEMM: C[M x 128] = act(A[M x K] @ Bt^T + bias)
// 32x128 block tile, 4 waves each compute 32x32. BK=64, XOR-swizzled LDS.
template <typename AT>
__global__ __launch_bounds__(256) void k_gemm32(const AT* __restrict__ A,
                                                const bf16_t* __restrict__ Bt,
                                                const float* __restrict__ bias,
                                                bf16_t* __restrict__ C,
                                                int M, int K, int doRelu) {
  __shared__ bf16_t As[32 * 64];
  __shared__ bf16_t Bs[128 * 64];
  const int t = threadIdx.x;
  const int wid = t >> 6;
  const int lane = t & 63;
  const int wn = wid * 32;
  const int l15 = lane & 15;
  const int quad = lane >> 4;
  const int rowBase = blockIdx.x * 32;

  f32x4 acc[2][2];
#pragma unroll
  for (int i = 0; i < 2; ++i)
#pragma unroll
    for (int j = 0; j < 2; ++j) {
      f32x4 z = {0.f, 0.f, 0.f, 0.f};
      acc[i][j] = z;
    }

  for (int k0 = 0; k0 < K; k0 += 64) {
    if constexpr (sizeof(AT) == 4) {
#pragma unroll
      for (int i = 0; i < 2; ++i) {
        int idx = t + i * 256;
        int row = idx >> 4;
        int col4 = idx & 15;
        int gr = rowBase + row;
        float4 v = make_float4(0.f, 0.f, 0.f, 0.f);
        if (gr < M) v = *(const float4*)(A + (size_t)gr * K + k0 + col4 * 4);
        bf16x4 w;
        w[0] = (bf16_t)v.x; w[1] = (bf16_t)v.y; w[2] = (bf16_t)v.z; w[3] = (bf16_t)v.w;
        int c = col4 >> 1;
        int off = row * 64 + ((c ^ (row & 7)) << 3) + ((col4 & 1) << 2);
        *(bf16x4*)&As[off] = w;
      }
    } else {
      int row = t >> 3;
      int c = t & 7;
      int gr = rowBase + row;
      bf16x8 v = {};
      if (gr < M) v = *(const bf16x8*)(A + (size_t)gr * K + k0 + c * 8);
      int off = row * 64 + ((c ^ (row & 7)) << 3);
      *(bf16x8*)&As[off] = v;
    }
#pragma unroll
    for (int i = 0; i < 4; ++i) {
      int idx = t + i * 256;
      int row = idx >> 3;
      int c = idx & 7;
      bf16x8 v = *(const bf16x8*)(Bt + (size_t)row * K + k0 + c * 8);
      int off = row * 64 + ((c ^ (row & 7)) << 3);
      *(bf16x8*)&Bs[off] = v;
    }
    __syncthreads();
#pragma unroll
    for (int kk = 0; kk < 2; ++kk) {
      bf16x8 af[2], bfr[2];
      int k8 = kk * 4 + quad;
#pragma unroll
      for (int mi = 0; mi < 2; ++mi) {
        int row = mi * 16 + l15;
        af[mi] = *(const bf16x8*)&As[row * 64 + ((k8 ^ (row & 7)) << 3)];
      }
#pragma unroll
      for (int ni = 0; ni < 2; ++ni) {
        int row = wn + ni * 16 + l15;
        bfr[ni] = *(const bf16x8*)&Bs[row * 64 + ((k8 ^ (row & 7)) << 3)];
      }
#pragma unroll
      for (int mi = 0; mi < 2; ++mi)
#pragma unroll
        for (int ni = 0; ni < 2; ++ni)
          acc[mi][ni] = __builtin_amdgcn_mfma_f32_16x16x32_bf16(af[mi], bfr[ni], acc[mi][ni], 0, 0, 0);
    }
    __syncthreads();
  }

#pragma unroll
  for (int mi = 0; mi < 2; ++mi) {
#pragma unroll
    for (int ni = 0; ni < 2; ++ni) {
      int col = wn + ni * 16 + l15;
      float bv = bias ? bias[col] : 0.f;
#pragma unroll
      for (int r = 0; r < 4; ++r) {
        int row = mi * 16 + quad * 4 + r;
        int gr = rowBase + row;
        if (gr < M) {
          float v = acc[mi][ni][r] + bv;
          if (doRelu) v = fmaxf(v, 0.f);
          C[(size_t)gr * HD + col] = (bf16_t)v;
        }
      }
    }
  }
}

// ---- CSR build
__global__ __launch_bounds__(256) void k_pos(const int* __restrict__ dst, int* __restrict__ cnt,
                                             int* __restrict__ pos, int E) {
  int e = blockIdx.x * 256 + threadIdx.x;
  if (e < E) pos[e] = atomicAdd(&cnt[dst[e]], 1);
}

__global__ __launch_bounds__(256) void k_scan1(const int* __restrict__ cnt, int* __restrict__ bsum, int n) {
  __shared__ int s[256];
  int t = threadIdx.x;
  int i = blockIdx.x * 256 + t;
  s[t] = (i < n) ? cnt[i] : 0;
  __syncthreads();
  for (int d = 128; d > 0; d >>= 1) {
    if (t < d) s[t] += s[t + d];
    __syncthreads();
  }
  if (t == 0) bsum[blockIdx.x] = s[0];
}

__global__ __launch_bounds__(256) void k_scan2(int* __restrict__ bsum, int nb) {
  __shared__ int s[256];
  int t = threadIdx.x;
  int v = (t < nb) ? bsum[t] : 0;
  s[t] = v;
  __syncthreads();
  for (int d = 1; d < 256; d <<= 1) {
    int x = (t >= d) ? s[t - d] : 0;
    __syncthreads();
    s[t] += x;
    __syncthreads();
  }
  if (t < nb) bsum[t] = s[t] - v;
  if (t == 255) bsum[nb] = s[255];
}

__global__ __launch_bounds__(256) void k_scan3(const int* __restrict__ cnt, const int* __restrict__ bsum,
                                               int* __restrict__ off, int n) {
  __shared__ int s[256];
  int t = threadIdx.x;
  int i = blockIdx.x * 256 + t;
  int v = (i < n) ? cnt[i] : 0;
  s[t] = v;
  __syncthreads();
  for (int d = 1; d < 256; d <<= 1) {
    int x = (t >= d) ? s[t - d] : 0;
    __syncthreads();
    s[t] += x;
    __syncthreads();
  }
  if (i < n) off[i] = bsum[blockIdx.x] + s[t] - v;
  if (i == n - 1) off[n] = bsum[blockIdx.x] + s[t];
}

__global__ __launch_bounds__(256) void k_fill(const int* __restrict__ src, const int* __restrict__ dst,
                                              const int* __restrict__ off, const int* __restrict__ pos,
                                              int* __restrict__ ssrc, int E) {
  int e = blockIdx.x * 256 + threadIdx.x;
  if (e >= E) return;
  ssrc[off[dst[e]] + pos[e]] = src[e];
}

// ---- CSR mean-aggregate v2, wave-per-node: 4 lane-groups x 16 lanes.
// Indices for the node are preloaded in ONE coalesced load (ssrc[b+lane]) and
// distributed via __shfl (register-resident) -> no index->gather dependency
// chain, and the 32-edge main chunk keeps 8 row-gathers in flight per lane
// (vs 2 before). Degree > 64 handled by a rare fallback tail.
__global__ __launch_bounds__(256) void k_aggregate(const bf16_t* __restrict__ h,
                                                   const int* __restrict__ ssrc,
                                                   const int* __restrict__ off,
                                                   bf16_t* __restrict__ agg, int n) {
  int node = blockIdx.x * 4 + (threadIdx.x >> 6);
  if (node >= n) return;
  int lane = threadIdx.x & 63;
  int g = lane >> 4;
  int fl = lane & 15;
  int b = off[node], e = off[node + 1];
  int deg = e - b;
  int d64 = min(deg, 64);
  int idxr = (lane < deg) ? ssrc[b + lane] : 0;
  float acc[8];
#pragma unroll
  for (int j = 0; j < 8; ++j) acc[j] = 0.f;
  const bf16_t* hp = h + fl * 8;

  int j0 = 0;
  // main chunk: 32 edges, 8 gathers in flight per lane
  for (; j0 + 32 <= d64; j0 += 32) {
    int s[8];
#pragma unroll
    for (int k = 0; k < 8; ++k) s[k] = __shfl(idxr, j0 + 4 * k + g);
    bf16x8 v[8];
#pragma unroll
    for (int k = 0; k < 8; ++k) v[k] = *(const bf16x8*)(hp + (size_t)s[k] * HD);
#pragma unroll
    for (int k = 0; k < 8; ++k)
#pragma unroll
      for (int jj = 0; jj < 8; ++jj) acc[jj] += (float)v[k][jj];
  }
  // 8-edge chunks
  for (; j0 + 8 <= d64; j0 += 8) {
    int s0 = __shfl(idxr, j0 + g);
    int s1 = __shfl(idxr, j0 + 4 + g);
    bf16x8 v0 = *(const bf16x8*)(hp + (size_t)s0 * HD);
    bf16x8 v1 = *(const bf16x8*)(hp + (size_t)s1 * HD);
#pragma unroll
    for (int jj = 0; jj < 8; ++jj) acc[jj] += (float)v0[jj] + (float)v1[jj];
  }
  // 4-edge chunk
  if (j0 + 4 <= d64) {
    int s0 = __shfl(idxr, j0 + g);
    bf16x8 v0 = *(const bf16x8*)(hp + (size_t)s0 * HD);
#pragma unroll
    for (int jj = 0; jj < 8; ++jj) acc[jj] += (float)v0[jj];
    j0 += 4;
  }
  // partial (<4) chunk
  if (j0 + g < d64) {
    int s0 = __shfl(idxr, j0 + g);
    bf16x8 v0 = *(const bf16x8*)(hp + (size_t)s0 * HD);
#pragma unroll
    for (int jj = 0; jj < 8; ++jj) acc[jj] += (float)v0[jj];
  }
  // rare tail: degree > 64
  for (int i = b + 64; i + g < e; i += 4) {
    int s0 = ssrc[i + g];
    bf16x8 v0 = *(const bf16x8*)(hp + (size_t)s0 * HD);
#pragma unroll
    for (int jj = 0; jj < 8; ++jj) acc[jj] += (float)v0[jj];
  }

#pragma unroll
  for (int j = 0; j < 8; ++j) {
    acc[j] += __shfl_xor(acc[j], 16);
    acc[j] += __shfl_xor(acc[j], 32);
  }
  if (g == 0) {
    float inv = (e > b) ? 1.f / (float)(e - b) : 0.f;
    bf16x8 o;
#pragma unroll
    for (int j = 0; j < 8; ++j) o[j] = (bf16_t)(acc[j] * inv);
    *(bf16x8*)(agg + (size_t)node * HD + fl * 8) = o;
  }
}

// ---- pool v2: 64-row chunks (782 blocks -> 4x the waves of the old 256-row version)
__global__ __launch_bounds__(128) void k_pool(const bf16_t* __restrict__ agg, const int* __restrict__ batch,
                                              float* __restrict__ p, float* __restrict__ gcnt, int n) {
  int base = blockIdx.x * 64;
  if (base >= n) return;
  int t = threadIdx.x;
  int end = min(base + 64, n);
  float acc = 0.f;
  int curg = batch[base];
  int runStart = base;
  for (int i = base; i < end; ++i) {
    int g = batch[i];
    if (g != curg) {
      atomicAdd(&p[curg * HD + t], acc);
      if (t == 0) atomicAdd(&gcnt[curg], (float)(i - runStart));
      acc = 0.f; curg = g; runStart = i;
    }
    acc += (float)agg[(size_t)i * HD + t];
  }
  atomicAdd(&p[curg * HD + t], acc);
  if (t == 0) atomicAdd(&gcnt[curg], (float)(end - runStart));
}

// ---- head
__global__ __launch_bounds__(128) void k_head(const float* __restrict__ p, const float* __restrict__ gcnt,
                                              const float* __restrict__ w3,
                                              const float* __restrict__ c1w, const float* __restrict__ c1b,
                                              const float* __restrict__ c2w, const float* __restrict__ c2b,
                                              const float* __restrict__ c3w, const float* __restrict__ c3b,
                                              float* __restrict__ out) {
  __shared__ float sa[128], sb[128];
  int g = blockIdx.x, t = threadIdx.x;
  float inv = 1.f / fmaxf(gcnt[g], 1.f);
  sa[t] = p[g * HD + t] * inv;
  __syncthreads();
  float z = 0.f;
  for (int k = 0; k < HD; ++k) z += sa[k] * w3[k * HD + t];
  z *= TP_NORM_F;
  out[128 + g * HD + t] = z;
  sb[t] = z;
  __syncthreads();
  float o1 = c1b[t];
  for (int k = 0; k < HD; ++k) o1 += sb[k] * c1w[k * HD + t];
  o1 = fmaxf(o1, 0.f);
  __syncthreads();
  sa[t] = o1;
  __syncthreads();
  float o2 = c2b[t];
  for (int k = 0; k < HD; ++k) o2 += sa[k] * c2w[k * HD + t];
  o2 = fmaxf(o2, 0.f);
  __syncthreads();
  sb[t] = o2;
  __syncthreads();
  if (t < 2) {
    float o = c3b[t];
    for (int k = 0; k < HD; ++k) o += sb[k] * c3w[k * 2 + t];
    out[g * 2 + t] = o;
  }
}

extern "C" void kernel_launch(void* const* d_in, const int* in_sizes, int n_in,
                              void* d_out, int out_size, void* d_ws, size_t ws_size,
                              hipStream_t stream) {
  const float* x = (const float*)d_in[0];
  const int* eidx = (const int*)d_in[2];
  const int* src = eidx;
  const int* dst = eidx + N_EDGES;
  const int* batch = (const int*)d_in[3];
  const float* lin_w = (const float*)d_in[4];
  const float* lin_b = (const float*)d_in[5];
  const float* tp_w1 = (const float*)d_in[6];
  const float* tp_w2 = (const float*)d_in[7];
  const float* tp_w3 = (const float*)d_in[8];
  const float* c1w = (const float*)d_in[9];
  const float* c1b = (const float*)d_in[10];
  const float* c2w = (const float*)d_in[11];
  const float* c2b = (const float*)d_in[12];
  const float* c3w = (const float*)d_in[13];
  const float* c3b = (const float*)d_in[14];
  float* out = (float*)d_out;
  (void)in_sizes; (void)n_in; (void)out_size; (void)ws_size;

  uintptr_t wp = (uintptr_t)d_ws;
  auto alloc = [&](size_t bytes) -> void* {
    uintptr_t a = (wp + 255) & ~(uintptr_t)255;
    wp = a + bytes;
    return (void*)a;
  };
  bf16_t* WtL  = (bf16_t*)alloc(sizeof(bf16_t) * (size_t)HD * FIN);
  bf16_t* Wt1  = (bf16_t*)alloc(sizeof(bf16_t) * (size_t)HD * HD);
  bf16_t* Wt2  = (bf16_t*)alloc(sizeof(bf16_t) * (size_t)HD * HD);
  bf16_t* h    = (bf16_t*)alloc(sizeof(bf16_t) * (size_t)50048 * HD);
  bf16_t* agg  = (bf16_t*)alloc(sizeof(bf16_t) * (size_t)50048 * HD);
  int*    cnt  = (int*)alloc(sizeof(int) * N_NODES);
  int*    bsum = (int*)alloc(sizeof(int) * 256);
  int*    offs = (int*)alloc(sizeof(int) * (N_NODES + 1));
  int*    pos  = (int*)alloc(sizeof(int) * N_EDGES);
  int*    ssrc = (int*)alloc(sizeof(int) * N_EDGES);
  float*  pbuf = (float*)alloc(sizeof(float) * NG * HD);
  float*  gcnt = (float*)alloc(sizeof(float) * NG);

  hipMemsetAsync(cnt, 0, sizeof(int) * N_NODES, stream);
  hipMemsetAsync(pbuf, 0, sizeof(float) * NG * HD, stream);
  hipMemsetAsync(gcnt, 0, sizeof(float) * NG, stream);

  k_prep<<<(FIN * HD + 2 * HD * HD + 255) / 256, 256, 0, stream>>>(lin_w, tp_w1, tp_w2, WtL, Wt1, Wt2);

  const int nScanBlocks = (N_NODES + 255) / 256;  // 196
  k_pos<<<(N_EDGES + 255) / 256, 256, 0, stream>>>(dst, cnt, pos, N_EDGES);
  k_scan1<<<nScanBlocks, 256, 0, stream>>>(cnt, bsum, N_NODES);
  k_scan2<<<1, 256, 0, stream>>>(bsum, nScanBlocks);
  k_scan3<<<nScanBlocks, 256, 0, stream>>>(cnt, bsum, offs, N_NODES);
  k_fill<<<(N_EDGES + 255) / 256, 256, 0, stream>>>(src, dst, offs, pos, ssrc, N_EDGES);

  const int gblocks = (N_NODES + 31) / 32;   // 1563
  const int ablocks = (N_NODES + 3) / 4;     // 12500

  // h0 = relu(x @ lin_w + b)
  k_gemm32<float><<<gblocks, 256, 0, stream>>>(x, WtL, lin_b, h, N_NODES, FIN, 1);

  // conv1
  k_aggregate<<<ablocks, 256, 0, stream>>>(h, ssrc, offs, agg, N_NODES);
  k_gemm32<bf16_t><<<gblocks, 256, 0, stream>>>(agg, Wt1, nullptr, h, N_NODES, HD, 1);
  // conv2
  k_aggregate<<<ablocks, 256, 0, stream>>>(h, ssrc, offs, agg, N_NODES);
  k_gemm32<bf16_t><<<gblocks, 256, 0, stream>>>(agg, Wt2, nullptr, h, N_NODES, HD, 1);
  // conv3 aggregation only (W3 folded into head)
  k_aggregate<<<ablocks, 256, 0, stream>>>(h, ssrc, offs, agg, N_NODES);

  k_pool<<<(N_NODES + 63) / 64, 128, 0, stream>>>(agg, batch, pbuf, gcnt, N_NODES);
  k_head<<<NG, 128, 0, stream>>>(pbuf, gcnt, tp_w3, c1w, c1b, c2w, c2b, c3w, c3b, out);
}

// Round 3
// 707.695 us; speedup vs baseline: 1.1124x; 1.0233x over previous
//
#include <hip/hip_runtime.h>
#include <hip/hip_bf16.h>

typedef __bf16 bf16_t;
typedef bf16_t bf16x4 __attribute__((ext_vector_type(4)));
typedef bf16_t bf16x8 __attribute__((ext_vector_type(8)));
typedef float f32x4 __attribute__((ext_vector_type(4)));

static constexpr int N_NODES = 50000;
static constexpr int N_EDGES = 1600000;
static constexpr int FIN = 1280;
static constexpr int HD = 128;
static constexpr int NG = 64;
// 0.5/sqrt(pi)/sqrt(128)
static constexpr float TP_NORM_F = 0.0249338908f;

// ---- packed: weight prep (768 blocks) + per-edge slot atomic (6250 blocks).
// prep also zeroes pbuf/gcnt (absorbs two memsets). cnt is zeroed by a
// preceding memset; stream order guarantees it before this kernel.
__global__ __launch_bounds__(256) void k_prep_pos(const float* __restrict__ lin_w,
                                                  const float* __restrict__ tp1,
                                                  const float* __restrict__ tp2,
                                                  bf16_t* __restrict__ WtL,
                                                  bf16_t* __restrict__ Wt1,
                                                  bf16_t* __restrict__ Wt2,
                                                  float* __restrict__ pbuf,
                                                  float* __restrict__ gcnt,
                                                  const int* __restrict__ dst,
                                                  int* __restrict__ cnt,
                                                  int* __restrict__ pos) {
  const int PREP_BLOCKS = 768;  // covers FIN*HD + 2*HD*HD = 196608 exactly
  if (blockIdx.x < PREP_BLOCKS) {
    int idx = blockIdx.x * 256 + threadIdx.x;
    const int totL = FIN * HD;      // 163840
    const int tot1 = HD * HD;       // 16384
    if (idx < totL) {
      int k = idx >> 7, n = idx & 127;
      WtL[n * FIN + k] = (bf16_t)lin_w[idx];
    } else if (idx < totL + tot1) {
      int j = idx - totL;
      int k = j >> 7, n = j & 127;
      Wt1[n * HD + k] = (bf16_t)(tp1[j] * TP_NORM_F);
    } else {
      int j = idx - totL - tot1;
      int k = j >> 7, n = j & 127;
      Wt2[n * HD + k] = (bf16_t)(tp2[j] * TP_NORM_F);
    }
    if (idx < NG * HD) pbuf[idx] = 0.f;
    if (idx < NG) gcnt[idx] = 0.f;
  } else {
    int e = (blockIdx.x - PREP_BLOCKS) * 256 + threadIdx.x;
    if (e < N_EDGES) pos[e] = atomicAdd(&cnt[dst[e]], 1);
  }
}

// ---- hierarchical scan (unchanged)
__global__ __launch_bounds__(256) void k_scan1(const int* __restrict__ cnt, int* __restrict__ bsum, int n) {
  __shared__ int s[256];
  int t = threadIdx.x;
  int i = blockIdx.x * 256 + t;
  s[t] = (i < n) ? cnt[i] : 0;
  __syncthreads();
  for (int d = 128; d > 0; d >>= 1) {
    if (t < d) s[t] += s[t + d];
    __syncthreads();
  }
  if (t == 0) bsum[blockIdx.x] = s[0];
}

__global__ __launch_bounds__(256) void k_scan2(int* __restrict__ bsum, int nb) {
  __shared__ int s[256];
  int t = threadIdx.x;
  int v = (t < nb) ? bsum[t] : 0;
  s[t] = v;
  __syncthreads();
  for (int d = 1; d < 256; d <<= 1) {
    int x = (t >= d) ? s[t - d] : 0;
    __syncthreads();
    s[t] += x;
    __syncthreads();
  }
  if (t < nb) bsum[t] = s[t] - v;
  if (t == 255) bsum[nb] = s[255];
}

__global__ __launch_bounds__(256) void k_scan3(const int* __restrict__ cnt, const int* __restrict__ bsum,
                                               int* __restrict__ off, int n) {
  __shared__ int s[256];
  int t = threadIdx.x;
  int i = blockIdx.x * 256 + t;
  int v = (i < n) ? cnt[i] : 0;
  s[t] = v;
  __syncthreads();
  for (int d = 1; d < 256; d <<= 1) {
    int x = (t >= d) ? s[t - d] : 0;
    __syncthreads();
    s[t] += x;
    __syncthreads();
  }
  if (i < n) off[i] = bsum[blockIdx.x] + s[t] - v;
  if (i == n - 1) off[n] = bsum[blockIdx.x] + s[t];
}

// ---- packed: lin GEMM (1563 blocks, 32x128 tile, K=1280) + CSR fill (6250 blocks).
// The scatter-fill is independent of the GEMM and hides under it.
__global__ __launch_bounds__(256) void k_lin_fill(const float* __restrict__ A,
                                                  const bf16_t* __restrict__ Bt,
                                                  const float* __restrict__ bias,
                                                  bf16_t* __restrict__ C,
                                                  const int* __restrict__ srcE,
                                                  const int* __restrict__ dstE,
                                                  const int* __restrict__ offn,
                                                  const int* __restrict__ pos,
                                                  int* __restrict__ ssrc) {
  __shared__ bf16_t As[32 * 64];
  __shared__ bf16_t Bs[128 * 64];
  const int GB = (N_NODES + 31) / 32;  // 1563
  if (blockIdx.x >= GB) {
    int e = (blockIdx.x - GB) * 256 + threadIdx.x;
    if (e < N_EDGES) ssrc[offn[dstE[e]] + pos[e]] = srcE[e];
    return;
  }
  const int M = N_NODES, K = FIN;
  const int t = threadIdx.x;
  const int wid = t >> 6;
  const int lane = t & 63;
  const int wn = wid * 32;
  const int l15 = lane & 15;
  const int quad = lane >> 4;
  const int rowBase = blockIdx.x * 32;

  f32x4 acc[2][2];
#pragma unroll
  for (int i = 0; i < 2; ++i)
#pragma unroll
    for (int j = 0; j < 2; ++j) {
      f32x4 z = {0.f, 0.f, 0.f, 0.f};
      acc[i][j] = z;
    }

  for (int k0 = 0; k0 < K; k0 += 64) {
#pragma unroll
    for (int i = 0; i < 2; ++i) {
      int idx = t + i * 256;
      int row = idx >> 4;
      int col4 = idx & 15;
      int gr = rowBase + row;
      float4 v = make_float4(0.f, 0.f, 0.f, 0.f);
      if (gr < M) v = *(const float4*)(A + (size_t)gr * K + k0 + col4 * 4);
      bf16x4 w;
      w[0] = (bf16_t)v.x; w[1] = (bf16_t)v.y; w[2] = (bf16_t)v.z; w[3] = (bf16_t)v.w;
      int c = col4 >> 1;
      int off = row * 64 + ((c ^ (row & 7)) << 3) + ((col4 & 1) << 2);
      *(bf16x4*)&As[off] = w;
    }
#pragma unroll
    for (int i = 0; i < 4; ++i) {
      int idx = t + i * 256;
      int row = idx >> 3;
      int c = idx & 7;
      bf16x8 v = *(const bf16x8*)(Bt + (size_t)row * K + k0 + c * 8);
      int off = row * 64 + ((c ^ (row & 7)) << 3);
      *(bf16x8*)&Bs[off] = v;
    }
    __syncthreads();
#pragma unroll
    for (int kk = 0; kk < 2; ++kk) {
      bf16x8 af[2], bfr[2];
      int k8 = kk * 4 + quad;
#pragma unroll
      for (int mi = 0; mi < 2; ++mi) {
        int row = mi * 16 + l15;
        af[mi] = *(const bf16x8*)&As[row * 64 + ((k8 ^ (row & 7)) << 3)];
      }
#pragma unroll
      for (int ni = 0; ni < 2; ++ni) {
        int row = wn + ni * 16 + l15;
        bfr[ni] = *(const bf16x8*)&Bs[row * 64 + ((k8 ^ (row & 7)) << 3)];
      }
#pragma unroll
      for (int mi = 0; mi < 2; ++mi)
#pragma unroll
        for (int ni = 0; ni < 2; ++ni)
          acc[mi][ni] = __builtin_amdgcn_mfma_f32_16x16x32_bf16(af[mi], bfr[ni], acc[mi][ni], 0, 0, 0);
    }
    __syncthreads();
  }

#pragma unroll
  for (int mi = 0; mi < 2; ++mi) {
#pragma unroll
    for (int ni = 0; ni < 2; ++ni) {
      int col = wn + ni * 16 + l15;
      float bv = bias[col];
#pragma unroll
      for (int r = 0; r < 4; ++r) {
        int row = mi * 16 + quad * 4 + r;
        int gr = rowBase + row;
        if (gr < M) {
          float v = acc[mi][ni][r] + bv;
          v = fmaxf(v, 0.f);
          C[(size_t)gr * HD + col] = (bf16_t)v;
        }
      }
    }
  }
}

// ---- fused conv: aggregate 32 nodes into LDS (swizzled) + 32x128x128 MFMA GEMM.
// Eliminates the agg global round-trip for conv1/conv2.
// LDS layout for K=128: treat as [row][half(2)][64] with the verified XOR
// swizzle within each 64-col half: off = (row*2+h)*64 + ((c ^ (row&7))<<3).
__global__ __launch_bounds__(256) void k_conv_fused(const bf16_t* __restrict__ hin,
                                                    const int* __restrict__ ssrc,
                                                    const int* __restrict__ off,
                                                    const bf16_t* __restrict__ Bt,
                                                    bf16_t* __restrict__ hout, int n) {
  __shared__ bf16_t As[32 * 128];
  __shared__ bf16_t Bs[128 * 128];
  const int t = threadIdx.x;
  const int wid = t >> 6;
  const int lane = t & 63;
  const int g = lane >> 4;
  const int fl = lane & 15;
  const int rowBase = blockIdx.x * 32;

  // stage B: 128x128 bf16 = 2048 chunks of 8; 8 per thread
#pragma unroll
  for (int i = 0; i < 8; ++i) {
    int idx = t + i * 256;
    int row = idx >> 4;   // 0..127
    int cc = idx & 15;    // chunk in row
    bf16x8 v = *(const bf16x8*)(Bt + (size_t)row * HD + cc * 8);
    int hh = cc >> 3, c = cc & 7;
    int ob = (row * 2 + hh) * 64 + ((c ^ (row & 7)) << 3);
    *(bf16x8*)&Bs[ob] = v;
  }

  // aggregate 8 nodes per wave into As
  const bf16_t* hp = hin + fl * 8;
  for (int i = 0; i < 8; ++i) {
    int localRow = wid * 8 + i;
    int node = rowBase + localRow;
    if (node >= n) break;
    int b = off[node], e = off[node + 1];
    int deg = e - b;
    int d64 = min(deg, 64);
    int idxr = (lane < deg) ? ssrc[b + lane] : 0;
    float acc[8];
#pragma unroll
    for (int j = 0; j < 8; ++j) acc[j] = 0.f;

    int j0 = 0;
    for (; j0 + 32 <= d64; j0 += 32) {
      int s[8];
#pragma unroll
      for (int k = 0; k < 8; ++k) s[k] = __shfl(idxr, j0 + 4 * k + g);
      bf16x8 v[8];
#pragma unroll
      for (int k = 0; k < 8; ++k) v[k] = *(const bf16x8*)(hp + (size_t)s[k] * HD);
#pragma unroll
      for (int k = 0; k < 8; ++k)
#pragma unroll
        for (int jj = 0; jj < 8; ++jj) acc[jj] += (float)v[k][jj];
    }
    for (; j0 + 8 <= d64; j0 += 8) {
      int s0 = __shfl(idxr, j0 + g);
      int s1 = __shfl(idxr, j0 + 4 + g);
      bf16x8 v0 = *(const bf16x8*)(hp + (size_t)s0 * HD);
      bf16x8 v1 = *(const bf16x8*)(hp + (size_t)s1 * HD);
#pragma unroll
      for (int jj = 0; jj < 8; ++jj) acc[jj] += (float)v0[jj] + (float)v1[jj];
    }
    if (j0 + 4 <= d64) {
      int s0 = __shfl(idxr, j0 + g);
      bf16x8 v0 = *(const bf16x8*)(hp + (size_t)s0 * HD);
#pragma unroll
      for (int jj = 0; jj < 8; ++jj) acc[jj] += (float)v0[jj];
      j0 += 4;
    }
    if (j0 + g < d64) {
      int s0 = __shfl(idxr, j0 + g);
      bf16x8 v0 = *(const bf16x8*)(hp + (size_t)s0 * HD);
#pragma unroll
      for (int jj = 0; jj < 8; ++jj) acc[jj] += (float)v0[jj];
    }
    for (int ii = b + 64; ii + g < e; ii += 4) {
      int s0 = ssrc[ii + g];
      bf16x8 v0 = *(const bf16x8*)(hp + (size_t)s0 * HD);
#pragma unroll
      for (int jj = 0; jj < 8; ++jj) acc[jj] += (float)v0[jj];
    }
#pragma unroll
    for (int j = 0; j < 8; ++j) {
      acc[j] += __shfl_xor(acc[j], 16);
      acc[j] += __shfl_xor(acc[j], 32);
    }
    if (g == 0) {
      float inv = (e > b) ? 1.f / (float)(e - b) : 0.f;
      bf16x8 o;
#pragma unroll
      for (int j = 0; j < 8; ++j) o[j] = (bf16_t)(acc[j] * inv);
      int hh = fl >> 3, c = fl & 7;
      int oa = (localRow * 2 + hh) * 64 + ((c ^ (localRow & 7)) << 3);
      *(bf16x8*)&As[oa] = o;
    }
  }
  __syncthreads();

  // GEMM: 32x128 outputs, K=128 in LDS
  const int wn = wid * 32;
  const int l15 = lane & 15;
  const int quad = lane >> 4;
  f32x4 acc[2][2];
#pragma unroll
  for (int i = 0; i < 2; ++i)
#pragma unroll
    for (int j = 0; j < 2; ++j) {
      f32x4 z = {0.f, 0.f, 0.f, 0.f};
      acc[i][j] = z;
    }
#pragma unroll
  for (int kk = 0; kk < 4; ++kk) {
    int k16 = kk * 4 + quad;  // 0..15
    int hh = k16 >> 3, c = k16 & 7;
    bf16x8 af[2], bfr[2];
#pragma unroll
    for (int mi = 0; mi < 2; ++mi) {
      int row = mi * 16 + l15;
      af[mi] = *(const bf16x8*)&As[(row * 2 + hh) * 64 + ((c ^ (row & 7)) << 3)];
    }
#pragma unroll
    for (int ni = 0; ni < 2; ++ni) {
      int row = wn + ni * 16 + l15;
      bfr[ni] = *(const bf16x8*)&Bs[(row * 2 + hh) * 64 + ((c ^ (row & 7)) << 3)];
    }
#pragma unroll
    for (int mi = 0; mi < 2; ++mi)
#pragma unroll
      for (int ni = 0; ni < 2; ++ni)
        acc[mi][ni] = __builtin_amdgcn_mfma_f32_16x16x32_bf16(af[mi], bfr[ni], acc[mi][ni], 0, 0, 0);
  }

#pragma unroll
  for (int mi = 0; mi < 2; ++mi) {
#pragma unroll
    for (int ni = 0; ni < 2; ++ni) {
      int col = wn + ni * 16 + l15;
#pragma unroll
      for (int r = 0; r < 4; ++r) {
        int row = mi * 16 + quad * 4 + r;
        int gr = rowBase + row;
        if (gr < n) {
          float v = fmaxf(acc[mi][ni][r], 0.f);
          hout[(size_t)gr * HD + col] = (bf16_t)v;
        }
      }
    }
  }
}

// ---- standalone CSR mean-aggregate (conv3 -> pool path)
__global__ __launch_bounds__(256) void k_aggregate(const bf16_t* __restrict__ h,
                                                   const int* __restrict__ ssrc,
                                                   const int* __restrict__ off,
                                                   bf16_t* __restrict__ agg, int n) {
  int node = blockIdx.x * 4 + (threadIdx.x >> 6);
  if (node >= n) return;
  int lane = threadIdx.x & 63;
  int g = lane >> 4;
  int fl = lane & 15;
  int b = off[node], e = off[node + 1];
  int deg = e - b;
  int d64 = min(deg, 64);
  int idxr = (lane < deg) ? ssrc[b + lane] : 0;
  float acc[8];
#pragma unroll
  for (int j = 0; j < 8; ++j) acc[j] = 0.f;
  const bf16_t* hp = h + fl * 8;

  int j0 = 0;
  for (; j0 + 32 <= d64; j0 += 32) {
    int s[8];
#pragma unroll
    for (int k = 0; k < 8; ++k) s[k] = __shfl(idxr, j0 + 4 * k + g);
    bf16x8 v[8];
#pragma unroll
    for (int k = 0; k < 8; ++k) v[k] = *(const bf16x8*)(hp + (size_t)s[k] * HD);
#pragma unroll
    for (int k = 0; k < 8; ++k)
#pragma unroll
      for (int jj = 0; jj < 8; ++jj) acc[jj] += (float)v[k][jj];
  }
  for (; j0 + 8 <= d64; j0 += 8) {
    int s0 = __shfl(idxr, j0 + g);
    int s1 = __shfl(idxr, j0 + 4 + g);
    bf16x8 v0 = *(const bf16x8*)(hp + (size_t)s0 * HD);
    bf16x8 v1 = *(const bf16x8*)(hp + (size_t)s1 * HD);
#pragma unroll
    for (int jj = 0; jj < 8; ++jj) acc[jj] += (float)v0[jj] + (float)v1[jj];
  }
  if (j0 + 4 <= d64) {
    int s0 = __shfl(idxr, j0 + g);
    bf16x8 v0 = *(const bf16x8*)(hp + (size_t)s0 * HD);
#pragma unroll
    for (int jj = 0; jj < 8; ++jj) acc[jj] += (float)v0[jj];
    j0 += 4;
  }
  if (j0 + g < d64) {
    int s0 = __shfl(idxr, j0 + g);
    bf16x8 v0 = *(const bf16x8*)(hp + (size_t)s0 * HD);
#pragma unroll
    for (int jj = 0; jj < 8; ++jj) acc[jj] += (float)v0[jj];
  }
  for (int i = b + 64; i + g < e; i += 4) {
    int s0 = ssrc[i + g];
    bf16x8 v0 = *(const bf16x8*)(hp + (size_t)s0 * HD);
#pragma unroll
    for (int jj = 0; jj < 8; ++jj) acc[jj] += (float)v0[jj];
  }

#pragma unroll
  for (int j = 0; j < 8; ++j) {
    acc[j] += __shfl_xor(acc[j], 16);
    acc[j] += __shfl_xor(acc[j], 32);
  }
  if (g == 0) {
    float inv = (e > b) ? 1.f / (float)(e - b) : 0.f;
    bf16x8 o;
#pragma unroll
    for (int j = 0; j < 8; ++j) o[j] = (bf16_t)(acc[j] * inv);
    *(bf16x8*)(agg + (size_t)node * HD + fl * 8) = o;
  }
}

// ---- pool: 64-row chunks
__global__ __launch_bounds__(128) void k_pool(const bf16_t* __restrict__ agg, const int* __restrict__ batch,
                                              float* __restrict__ p, float* __restrict__ gcnt, int n) {
  int base = blockIdx.x * 64;
  if (base >= n) return;
  int t = threadIdx.x;
  int end = min(base + 64, n);
  float acc = 0.f;
  int curg = batch[base];
  int runStart = base;
  for (int i = base; i < end; ++i) {
    int g = batch[i];
    if (g != curg) {
      atomicAdd(&p[curg * HD + t], acc);
      if (t == 0) atomicAdd(&gcnt[curg], (float)(i - runStart));
      acc = 0.f; curg = g; runStart = i;
    }
    acc += (float)agg[(size_t)i * HD + t];
  }
  atomicAdd(&p[curg * HD + t], acc);
  if (t == 0) atomicAdd(&gcnt[curg], (float)(end - runStart));
}

// ---- head
__global__ __launch_bounds__(128) void k_head(const float* __restrict__ p, const float* __restrict__ gcnt,
                                              const float* __restrict__ w3,
                                              const float* __restrict__ c1w, const float* __restrict__ c1b,
                                              const float* __restrict__ c2w, const float* __restrict__ c2b,
                                              const float* __restrict__ c3w, const float* __restrict__ c3b,
                                              float* __restrict__ out) {
  __shared__ float sa[128], sb[128];
  int g = blockIdx.x, t = threadIdx.x;
  float inv = 1.f / fmaxf(gcnt[g], 1.f);
  sa[t] = p[g * HD + t] * inv;
  __syncthreads();
  float z = 0.f;
  for (int k = 0; k < HD; ++k) z += sa[k] * w3[k * HD + t];
  z *= TP_NORM_F;
  out[128 + g * HD + t] = z;
  sb[t] = z;
  __syncthreads();
  float o1 = c1b[t];
  for (int k = 0; k < HD; ++k) o1 += sb[k] * c1w[k * HD + t];
  o1 = fmaxf(o1, 0.f);
  __syncthreads();
  sa[t] = o1;
  __syncthreads();
  float o2 = c2b[t];
  for (int k = 0; k < HD; ++k) o2 += sa[k] * c2w[k * HD + t];
  o2 = fmaxf(o2, 0.f);
  __syncthreads();
  sb[t] = o2;
  __syncthreads();
  if (t < 2) {
    float o = c3b[t];
    for (int k = 0; k < HD; ++k) o += sb[k] * c3w[k * 2 + t];
    out[g * 2 + t] = o;
  }
}

extern "C" void kernel_launch(void* const* d_in, const int* in_sizes, int n_in,
                              void* d_out, int out_size, void* d_ws, size_t ws_size,
                              hipStream_t stream) {
  const float* x = (const float*)d_in[0];
  const int* eidx = (const int*)d_in[2];
  const int* src = eidx;
  const int* dst = eidx + N_EDGES;
  const int* batch = (const int*)d_in[3];
  const float* lin_w = (const float*)d_in[4];
  const float* lin_b = (const float*)d_in[5];
  const float* tp_w1 = (const float*)d_in[6];
  const float* tp_w2 = (const float*)d_in[7];
  const float* tp_w3 = (const float*)d_in[8];
  const float* c1w = (const float*)d_in[9];
  const float* c1b = (const float*)d_in[10];
  const float* c2w = (const float*)d_in[11];
  const float* c2b = (const float*)d_in[12];
  const float* c3w = (const float*)d_in[13];
  const float* c3b = (const float*)d_in[14];
  float* out = (float*)d_out;
  (void)in_sizes; (void)n_in; (void)out_size; (void)ws_size;

  uintptr_t wp = (uintptr_t)d_ws;
  auto alloc = [&](size_t bytes) -> void* {
    uintptr_t a = (wp + 255) & ~(uintptr_t)255;
    wp = a + bytes;
    return (void*)a;
  };
  bf16_t* WtL  = (bf16_t*)alloc(sizeof(bf16_t) * (size_t)HD * FIN);
  bf16_t* Wt1  = (bf16_t*)alloc(sizeof(bf16_t) * (size_t)HD * HD);
  bf16_t* Wt2  = (bf16_t*)alloc(sizeof(bf16_t) * (size_t)HD * HD);
  bf16_t* h    = (bf16_t*)alloc(sizeof(bf16_t) * (size_t)50048 * HD);
  bf16_t* agg  = (bf16_t*)alloc(sizeof(bf16_t) * (size_t)50048 * HD);
  int*    cnt  = (int*)alloc(sizeof(int) * N_NODES);
  int*    bsum = (int*)alloc(sizeof(int) * 256);
  int*    offs = (int*)alloc(sizeof(int) * (N_NODES + 1));
  int*    pos  = (int*)alloc(sizeof(int) * N_EDGES);
  int*    ssrc = (int*)alloc(sizeof(int) * N_EDGES);
  float*  pbuf = (float*)alloc(sizeof(float) * NG * HD);
  float*  gcnt = (float*)alloc(sizeof(float) * NG);

  hipMemsetAsync(cnt, 0, sizeof(int) * N_NODES, stream);

  const int posBlocks = (N_EDGES + 255) / 256;  // 6250
  k_prep_pos<<<768 + posBlocks, 256, 0, stream>>>(lin_w, tp_w1, tp_w2, WtL, Wt1, Wt2,
                                                  pbuf, gcnt, dst, cnt, pos);

  const int nScanBlocks = (N_NODES + 255) / 256;  // 196
  k_scan1<<<nScanBlocks, 256, 0, stream>>>(cnt, bsum, N_NODES);
  k_scan2<<<1, 256, 0, stream>>>(bsum, nScanBlocks);
  k_scan3<<<nScanBlocks, 256, 0, stream>>>(cnt, bsum, offs, N_NODES);

  const int gblocks = (N_NODES + 31) / 32;   // 1563
  // packed: h0 = relu(x @ lin_w + b)  ||  ssrc fill
  k_lin_fill<<<gblocks + posBlocks, 256, 0, stream>>>(x, WtL, lin_b, h, src, dst, offs, pos, ssrc);

  // conv1, conv2 fused (aggregate->LDS->GEMM), ping-pong h/agg as buffers
  k_conv_fused<<<gblocks, 256, 0, stream>>>(h, ssrc, offs, Wt1, agg, N_NODES);
  k_conv_fused<<<gblocks, 256, 0, stream>>>(agg, ssrc, offs, Wt2, h, N_NODES);
  // conv3 aggregation only (W3 folded into head)
  k_aggregate<<<(N_NODES + 3) / 4, 256, 0, stream>>>(h, ssrc, offs, agg, N_NODES);

  k_pool<<<(N_NODES + 63) / 64, 128, 0, stream>>>(agg, batch, pbuf, gcnt, N_NODES);
  k_head<<<NG, 128, 0, stream>>>(pbuf, gcnt, tp_w3, c1w, c1b, c2w, c2b, c3w, c3b, out);
}